// Round 2
// baseline (291.145 us; speedup 1.0000x reference)
//
#include <hip/hip_runtime.h>

// Reprojection residual:
//   pts = points_3d[point_indices]; cam = pose[camera_indices]
//   q = normalize(cam[:4]); uv = 2*cross(qv, pts)
//   rot = pts + w*uv + cross(qv, uv) + cam[4:7]
//   pix = (rot @ K.T); out = pix[:, :2]/pix[:, 2:] - points_2d
//
// Memory-bound streaming: 64MB p2d + 64MB idx + 64MB out + ~12MB gathered
// points_3d (L3-cached) + tiny pose/K. Process 2 obs/thread -> float4/int2
// vectorized streams (16B/8B per lane).

__device__ __forceinline__ void reproj_one(
    int c, int p,
    const float* __restrict__ pose,
    const float* __restrict__ pts3d,
    float K00, float K01, float K02,
    float K10, float K11, float K12,
    float K20, float K21, float K22,
    float& outx, float& outy)
{
    const float* cam = pose + 7 * c;
    float qw = cam[0], qx = cam[1], qy = cam[2], qz = cam[3];
    float tx = cam[4], ty = cam[5], tz = cam[6];

    float inv = 1.0f / sqrtf(qw*qw + qx*qx + qy*qy + qz*qz);
    qw *= inv; qx *= inv; qy *= inv; qz *= inv;

    const float* pt = pts3d + 3 * p;
    float x = pt[0], y = pt[1], z = pt[2];

    // uv = 2 * cross(qv, pt)
    float uvx = 2.0f * (qy*z - qz*y);
    float uvy = 2.0f * (qz*x - qx*z);
    float uvz = 2.0f * (qx*y - qy*x);

    // rot = pt + w*uv + cross(qv, uv) + t
    float rx = x + qw*uvx + (qy*uvz - qz*uvy) + tx;
    float ry = y + qw*uvy + (qz*uvx - qx*uvz) + ty;
    float rz = z + qw*uvz + (qx*uvy - qy*uvx) + tz;

    // pix = rot @ K.T
    float px = K00*rx + K01*ry + K02*rz;
    float py = K10*rx + K11*ry + K12*rz;
    float pz = K20*rx + K21*ry + K22*rz;

    outx = px / pz;
    outy = py / pz;
}

__global__ void __launch_bounds__(256)
reproj_kernel(const float4* __restrict__ p2d,      // 2 obs per float4
              const float*  __restrict__ K,
              const float*  __restrict__ pose,
              const float*  __restrict__ pts3d,
              const int2*   __restrict__ camIdx,
              const int2*   __restrict__ ptIdx,
              float4*       __restrict__ out,
              int nPairs)
{
    // K is uniform + cached; load once per thread.
    float K00 = K[0], K01 = K[1], K02 = K[2];
    float K10 = K[3], K11 = K[4], K12 = K[5];
    float K20 = K[6], K21 = K[7], K22 = K[8];

    int stride = gridDim.x * blockDim.x;
    for (int i = blockIdx.x * blockDim.x + threadIdx.x; i < nPairs; i += stride) {
        float4 p  = p2d[i];
        int2   ci = camIdx[i];
        int2   pi = ptIdx[i];

        float ax, ay, bx, by;
        reproj_one(ci.x, pi.x, pose, pts3d,
                   K00, K01, K02, K10, K11, K12, K20, K21, K22, ax, ay);
        reproj_one(ci.y, pi.y, pose, pts3d,
                   K00, K01, K02, K10, K11, K12, K20, K21, K22, bx, by);

        out[i] = make_float4(ax - p.x, ay - p.y, bx - p.z, by - p.w);
    }
}

extern "C" void kernel_launch(void* const* d_in, const int* in_sizes, int n_in,
                              void* d_out, int out_size, void* d_ws, size_t ws_size,
                              hipStream_t stream)
{
    const float* points_2d = (const float*)d_in[0];   // (N_OBS, 2) f32
    const float* K         = (const float*)d_in[1];   // (3,3) f32
    const float* pose      = (const float*)d_in[2];   // (N_CAMS, 7) f32
    const float* points_3d = (const float*)d_in[3];   // (N_PTS, 3) f32
    const int*   camIdx    = (const int*)d_in[4];     // (N_OBS,) i32
    const int*   ptIdx     = (const int*)d_in[5];     // (N_OBS,) i32
    float*       out       = (float*)d_out;           // (N_OBS, 2) f32

    int nObs   = in_sizes[4];          // 8,000,000
    int nPairs = nObs / 2;             // even: 4,000,000

    const int block = 256;
    int grid = (nPairs + block - 1) / block;
    if (grid > 2048) grid = 2048;      // grid-stride the rest

    reproj_kernel<<<grid, block, 0, stream>>>(
        (const float4*)points_2d, K, pose, points_3d,
        (const int2*)camIdx, (const int2*)ptIdx,
        (float4*)out, nPairs);
}

// Round 5
// 280.067 us; speedup vs baseline: 1.0396x; 1.0396x over previous
//
#include <hip/hip_runtime.h>

// Reprojection residual (see ref): gather pose+point per obs, quat-rotate,
// project with K, perspective divide, subtract observed pixel.
//
// R2 counters: 172us, FETCH 442MB (vs 140MB ideal), 3 TB/s, VALUBusy 13%.
// Diagnosis: points_3d (12MB) misses 4MB/XCD L2 on random gathers (~310MB
// refetch); grid-stride loop serialized the gather chains (low MLP).
// R4: same plan as R3 (exact grid for MLP + nontemporal streams), with
// ext_vector_type typedefs because __builtin_nontemporal_* rejects
// HIP_vector_type structs (int2/float4).

typedef int   i32x2 __attribute__((ext_vector_type(2)));
typedef float f32x4 __attribute__((ext_vector_type(4)));

__global__ void __launch_bounds__(256, 8)
reproj_kernel(const f32x4* __restrict__ p2d,      // 2 obs per vec4
              const float* __restrict__ K,
              const float* __restrict__ pose,
              const float* __restrict__ pts3d,
              const i32x2* __restrict__ camIdx,
              const i32x2* __restrict__ ptIdx,
              f32x4*       __restrict__ out,
              int nPairs)
{
    int i = blockIdx.x * blockDim.x + threadIdx.x;
    if (i >= nPairs) return;

    // Streaming traffic: nontemporal (never re-read; keep caches for table).
    i32x2 ci = __builtin_nontemporal_load(&camIdx[i]);
    i32x2 pi = __builtin_nontemporal_load(&ptIdx[i]);
    f32x4 p  = __builtin_nontemporal_load(&p2d[i]);

    // K is tiny + uniform: plain (cached) loads.
    float K00 = K[0], K01 = K[1], K02 = K[2];
    float K10 = K[3], K11 = K[4], K12 = K[5];
    float K20 = K[6], K21 = K[7], K22 = K[8];

    auto project = [&](int c, int pidx, float& ox, float& oy) {
        const float* cam = pose + 7 * c;
        float qw = cam[0], qx = cam[1], qy = cam[2], qz = cam[3];
        float tx = cam[4], ty = cam[5], tz = cam[6];

        float inv = 1.0f / sqrtf(qw*qw + qx*qx + qy*qy + qz*qz);
        qw *= inv; qx *= inv; qy *= inv; qz *= inv;

        const float* pt = pts3d + 3 * pidx;
        float x = pt[0], y = pt[1], z = pt[2];

        float uvx = 2.0f * (qy*z - qz*y);
        float uvy = 2.0f * (qz*x - qx*z);
        float uvz = 2.0f * (qx*y - qy*x);

        float rx = x + qw*uvx + (qy*uvz - qz*uvy) + tx;
        float ry = y + qw*uvy + (qz*uvx - qx*uvz) + ty;
        float rz = z + qw*uvz + (qx*uvy - qy*uvx) + tz;

        float px = K00*rx + K01*ry + K02*rz;
        float py = K10*rx + K11*ry + K12*rz;
        float pz = K20*rx + K21*ry + K22*rz;

        ox = px / pz;
        oy = py / pz;
    };

    float ax, ay, bx, by;
    project(ci.x, pi.x, ax, ay);
    project(ci.y, pi.y, bx, by);

    f32x4 r;
    r.x = ax - p.x; r.y = ay - p.y; r.z = bx - p.z; r.w = by - p.w;
    __builtin_nontemporal_store(r, &out[i]);
}

extern "C" void kernel_launch(void* const* d_in, const int* in_sizes, int n_in,
                              void* d_out, int out_size, void* d_ws, size_t ws_size,
                              hipStream_t stream)
{
    const float* points_2d = (const float*)d_in[0];   // (N_OBS, 2) f32
    const float* K         = (const float*)d_in[1];   // (3,3) f32
    const float* pose      = (const float*)d_in[2];   // (N_CAMS, 7) f32
    const float* points_3d = (const float*)d_in[3];   // (N_PTS, 3) f32
    const int*   camIdx    = (const int*)d_in[4];     // (N_OBS,) i32
    const int*   ptIdx     = (const int*)d_in[5];     // (N_OBS,) i32
    float*       out       = (float*)d_out;           // (N_OBS, 2) f32

    int nObs   = in_sizes[4];          // 8,000,000
    int nPairs = nObs / 2;             // 4,000,000 (even)

    const int block = 256;
    int grid = (nPairs + block - 1) / block;   // exact: 15625 blocks

    reproj_kernel<<<grid, block, 0, stream>>>(
        (const f32x4*)points_2d, K, pose, points_3d,
        (const i32x2*)camIdx, (const i32x2*)ptIdx,
        (f32x4*)out, nPairs);
}

// Round 7
// 268.028 us; speedup vs baseline: 1.0862x; 1.0449x over previous
//
#include <hip/hip_runtime.h>

// Reprojection residual. R5 measured: 152us, FETCH 418MB, 3.2TB/s, VALU 15%,
// occ 77%. Bandwidth model fails (streams=30us; L3-resident gathers).
// TA model fits: 20 divergent VMEM instrs/thread x 64 addrs ~= 130us at
// ~1 addr/cy/CU. R6: reduce divergent VMEM 20 -> 6 per thread, same bytes:
//   pose  = 2x overlapping dwordx4 (28B row, both windows in-bounds)
//   point = 1x dwordx4 at 12p (rare last-point lane shifts by -4B)
// Streams stay nontemporal. Prediction: 55-75us if TA-bound; flat if
// fabric-bound.

typedef int   i32x2 __attribute__((ext_vector_type(2)));
typedef float f32x4 __attribute__((ext_vector_type(4)));
// 4-byte-aligned view so clang emits global_load_dwordx4 at dword alignment.
typedef float f32x4a __attribute__((ext_vector_type(4), aligned(4)));

__global__ void __launch_bounds__(256, 8)
reproj_kernel(const f32x4* __restrict__ p2d,      // 2 obs per vec4
              const float* __restrict__ K,
              const float* __restrict__ pose,     // (2000,7)
              const float* __restrict__ pts3d,    // (1e6,3)
              const i32x2* __restrict__ camIdx,
              const i32x2* __restrict__ ptIdx,
              f32x4*       __restrict__ out,
              int nPairs, int nPts)
{
    int i = blockIdx.x * blockDim.x + threadIdx.x;
    if (i >= nPairs) return;

    // Streaming traffic: nontemporal (never re-read; keep caches for tables).
    i32x2 ci = __builtin_nontemporal_load(&camIdx[i]);
    i32x2 pi = __builtin_nontemporal_load(&ptIdx[i]);
    f32x4 p  = __builtin_nontemporal_load(&p2d[i]);

    // K: tiny, uniform, cached.
    float K00 = K[0], K01 = K[1], K02 = K[2];
    float K10 = K[3], K11 = K[4], K12 = K[5];
    float K20 = K[6], K21 = K[7], K22 = K[8];

    auto project = [&](int c, int pidx, float& ox, float& oy) {
        // pose row = 28B. Two 16B windows, both in-bounds for c<=1999:
        //   [28c,28c+16) and [28c+12,28c+28) <= 56000.
        f32x4 q4 = *(const f32x4a*)(pose + 7 * c);       // qw qx qy qz
        f32x4 t4 = *(const f32x4a*)(pose + 7 * c + 3);   // qz tx ty tz
        float qw = q4.x, qx = q4.y, qy = q4.z, qz = q4.w;
        float tx = t4.y, ty = t4.z, tz = t4.w;

        float inv = 1.0f / sqrtf(qw*qw + qx*qx + qy*qy + qz*qz);
        qw *= inv; qx *= inv; qy *= inv; qz *= inv;

        // point row = 12B; one 16B load. Last point: shift window -4B.
        float x, y, z;
        if (pidx < nPts - 1) {
            f32x4 v = *(const f32x4a*)(pts3d + 3 * pidx);
            x = v.x; y = v.y; z = v.z;
        } else {
            f32x4 v = *(const f32x4a*)(pts3d + 3 * pidx - 1);
            x = v.y; y = v.z; z = v.w;
        }

        float uvx = 2.0f * (qy*z - qz*y);
        float uvy = 2.0f * (qz*x - qx*z);
        float uvz = 2.0f * (qx*y - qy*x);

        float rx = x + qw*uvx + (qy*uvz - qz*uvy) + tx;
        float ry = y + qw*uvy + (qz*uvx - qx*uvz) + ty;
        float rz = z + qw*uvz + (qx*uvy - qy*uvx) + tz;

        float px = K00*rx + K01*ry + K02*rz;
        float py = K10*rx + K11*ry + K12*rz;
        float pz = K20*rx + K21*ry + K22*rz;

        ox = px / pz;
        oy = py / pz;
    };

    float ax, ay, bx, by;
    project(ci.x, pi.x, ax, ay);
    project(ci.y, pi.y, bx, by);

    f32x4 r;
    r.x = ax - p.x; r.y = ay - p.y; r.z = bx - p.z; r.w = by - p.w;
    __builtin_nontemporal_store(r, &out[i]);
}

extern "C" void kernel_launch(void* const* d_in, const int* in_sizes, int n_in,
                              void* d_out, int out_size, void* d_ws, size_t ws_size,
                              hipStream_t stream)
{
    const float* points_2d = (const float*)d_in[0];   // (N_OBS, 2) f32
    const float* K         = (const float*)d_in[1];   // (3,3) f32
    const float* pose      = (const float*)d_in[2];   // (N_CAMS, 7) f32
    const float* points_3d = (const float*)d_in[3];   // (N_PTS, 3) f32
    const int*   camIdx    = (const int*)d_in[4];     // (N_OBS,) i32
    const int*   ptIdx     = (const int*)d_in[5];     // (N_OBS,) i32
    float*       out       = (float*)d_out;           // (N_OBS, 2) f32

    int nObs   = in_sizes[4];          // 8,000,000
    int nPairs = nObs / 2;             // 4,000,000 (even)
    int nPts   = in_sizes[3] / 3;      // 1,000,000

    const int block = 256;
    int grid = (nPairs + block - 1) / block;   // exact: 15625 blocks

    reproj_kernel<<<grid, block, 0, stream>>>(
        (const f32x4*)points_2d, K, pose, points_3d,
        (const i32x2*)camIdx, (const i32x2*)ptIdx,
        (f32x4*)out, nPairs, nPts);
}